// Round 1
// baseline (460.673 us; speedup 1.0000x reference)
//
#include <hip/hip_runtime.h>
#include <hip/hip_bf16.h>
#include <stdint.h>

typedef unsigned short u16;
typedef float f32x4 __attribute__((ext_vector_type(4)));
typedef __bf16 bf16x8 __attribute__((ext_vector_type(8)));
typedef unsigned short u16x8 __attribute__((ext_vector_type(8)));
typedef float f32x4v __attribute__((ext_vector_type(4)));

#define T_SEQ 2048
#define EMB   2048
#define NH    16
#define NKV   4
#define HD    128

__device__ __forceinline__ u16 f2bf(float f) {
    unsigned int u = __float_as_uint(f);
    unsigned int r = (u + 0x7fffu + ((u >> 16) & 1u)) >> 16;
    return (u16)r;
}
__device__ __forceinline__ float bf2f(u16 b) {
    return __uint_as_float(((unsigned int)b) << 16);
}

__device__ __forceinline__ void gload_lds16(const void* g, void* l) {
    __builtin_amdgcn_global_load_lds(
        (__attribute__((address_space(1))) void*)(g),
        (__attribute__((address_space(3))) void*)(l), 16, 0, 0);
}

// ---------------- cast x (f32 -> bf16), 8 elems/thread ----------------
__global__ void cast_f32_bf16(const float* __restrict__ in, u16* __restrict__ out, int n8) {
    int i = blockIdx.x * blockDim.x + threadIdx.x;
    if (i >= n8) return;
    const f32x4v* p = (const f32x4v*)(in + (size_t)i * 8);
    f32x4v a = p[0], b = p[1];
    u16x8 v;
    v[0]=f2bf(a.x); v[1]=f2bf(a.y); v[2]=f2bf(a.z); v[3]=f2bf(a.w);
    v[4]=f2bf(b.x); v[5]=f2bf(b.y); v[6]=f2bf(b.z); v[7]=f2bf(b.w);
    *(u16x8*)(out + (size_t)i * 8) = v;
}

// ------------- transpose-cast W (f32 KxN row-major -> bf16 NxK) -------------
// K fixed = 2048. Tile 64x64. Wt already offset to destination row block base.
__global__ void transpose_cast(const float* __restrict__ W, u16* __restrict__ Wt, int N) {
    __shared__ alignas(16) float sW[64 * 68];
    const int t = threadIdx.x;
    const int k0 = blockIdx.x * 64, n0 = blockIdx.y * 64;
#pragma unroll
    for (int i = 0; i < 4; i++) {
        int kr = i * 16 + (t >> 4), nc = (t & 15) * 4;
        *(f32x4v*)&sW[kr * 68 + nc] = *(const f32x4v*)&W[(size_t)(k0 + kr) * N + n0 + nc];
    }
    __syncthreads();
#pragma unroll
    for (int i = 0; i < 2; i++) {
        int nr = i * 32 + (t >> 3), kc = (t & 7) * 8;
        u16x8 v;
#pragma unroll
        for (int j = 0; j < 8; j++) v[j] = f2bf(sW[(kc + j) * 68 + nr]);
        *(u16x8*)&Wt[(size_t)(n0 + nr) * 2048 + k0 + kc] = v;
    }
}

// ---------------- GEMM: C[MxN] = A[MxK] * Bt[NxK]^T  (bf16 in, f32 acc) ----------------
// m97 structure: 128x128 tile, BK=32, 4 waves (each 64x64), global_load_lds w16.
template <bool OUT_F32>
__global__ __launch_bounds__(256) void gemm_bt(const u16* __restrict__ A, const u16* __restrict__ Bt,
                                               void* __restrict__ C, int M, int N, int K) {
    __shared__ alignas(16) u16 sA[128 * 32];
    __shared__ alignas(16) u16 sB[128 * 32];
    const int t = threadIdx.x;
    const int wave = t >> 6, lane = t & 63;
    const int l15 = lane & 15, hl = lane >> 4;
    const int m0 = blockIdx.x * 128, n0 = blockIdx.y * 128;
    const int wr = wave >> 1, wc = wave & 1;

    f32x4 acc[4][4];
    f32x4 z = {0.f, 0.f, 0.f, 0.f};
#pragma unroll
    for (int m = 0; m < 4; m++)
#pragma unroll
        for (int n = 0; n < 4; n++) acc[m][n] = z;

    const u16* gA = A + (size_t)m0 * K;
    const u16* gB = Bt + (size_t)n0 * K;
    const int rowA = t >> 2;          // 0..63
    const int colb = (t & 3) * 8;

    for (int k0 = 0; k0 < K; k0 += 32) {
#pragma unroll
        for (int i = 0; i < 2; i++) {
            gload_lds16(gA + (size_t)(i * 64 + rowA) * K + k0 + colb,
                        (char*)sA + i * 4096 + wave * 1024);
            gload_lds16(gB + (size_t)(i * 64 + rowA) * K + k0 + colb,
                        (char*)sB + i * 4096 + wave * 1024);
        }
        __syncthreads();
        bf16x8 af[4], bfm[4];
#pragma unroll
        for (int m = 0; m < 4; m++)
            af[m] = *(const bf16x8*)&sA[(wr * 64 + m * 16 + l15) * 32 + hl * 8];
#pragma unroll
        for (int n = 0; n < 4; n++)
            bfm[n] = *(const bf16x8*)&sB[(wc * 64 + n * 16 + l15) * 32 + hl * 8];
#pragma unroll
        for (int m = 0; m < 4; m++)
#pragma unroll
            for (int n = 0; n < 4; n++)
                acc[m][n] = __builtin_amdgcn_mfma_f32_16x16x32_bf16(af[m], bfm[n], acc[m][n], 0, 0, 0);
        __syncthreads();
    }
#pragma unroll
    for (int m = 0; m < 4; m++)
#pragma unroll
        for (int n = 0; n < 4; n++)
#pragma unroll
            for (int r = 0; r < 4; r++) {
                int row = m0 + wr * 64 + m * 16 + hl * 4 + r;
                int col = n0 + wc * 64 + n * 16 + l15;
                float v = acc[m][n][r];
                if (OUT_F32) ((float*)C)[(size_t)row * N + col] = v;
                else         ((u16*)C)[(size_t)row * N + col] = f2bf(v);
            }
}

// ---------------- RoPE on QKV buffer (in place, Q heads + K heads) ----------------
// out[d]    = x[d]*cos(t*invf[d/2])      - x[d+64]*sin(t*invf[d/2])        (d<64)
// out[d+64] = x[d+64]*cos(t*invf[32+d/2]) + x[d]*sin(t*invf[32+d/2])
__global__ void rope_kernel(u16* __restrict__ qkv, const int* __restrict__ pos) {
    int tid = blockIdx.x * 256 + threadIdx.x;
    int j = tid & 63;
    int rest = tid >> 6;
    int slice = rest % 20;
    int row = rest / 20;
    if (row >= 2 * T_SEQ) return;
    float tpos = (float)((row % T_SEQ) + pos[0]);
    int base = (slice < 16) ? slice * 128 : 2048 + (slice - 16) * 128;
    u16* p = qkv + (size_t)row * 3072 + base;
    float x1 = bf2f(p[j]), x2 = bf2f(p[j + 64]);
    const float c0 = 0.20762050593045702f;   // log2(10000)/64
    int i = j >> 1;
    float fA = tpos * exp2f(-(float)i * c0);
    float fB = tpos * exp2f(-(float)(32 + i) * c0);
    float o1 = x1 * cosf(fA) - x2 * sinf(fA);
    float o2 = x2 * cosf(fB) + x1 * sinf(fB);
    p[j] = f2bf(o1);
    p[j + 64] = f2bf(o2);
}

// ---------------- V transpose: QKV V-cols -> Vt[b][kh][d][t] ----------------
__global__ void vtrans(const u16* __restrict__ qkv, u16* __restrict__ vt) {
    __shared__ alignas(16) u16 sT[64 * 72];
    const int t = threadIdx.x;
    const int t0 = blockIdx.x * 64;
    const int d0 = blockIdx.y * 64;
    const int kh = blockIdx.z & 3, b = blockIdx.z >> 2;
#pragma unroll
    for (int i = 0; i < 2; i++) {
        int tr = i * 32 + (t >> 3), dc = (t & 7) * 8;
        *(u16x8*)&sT[tr * 72 + dc] =
            *(const u16x8*)&qkv[(size_t)(b * T_SEQ + t0 + tr) * 3072 + 2560 + kh * 128 + d0 + dc];
    }
    __syncthreads();
#pragma unroll
    for (int i = 0; i < 2; i++) {
        int dr = i * 32 + (t >> 3), tc = (t & 7) * 8;
        u16x8 v;
#pragma unroll
        for (int j = 0; j < 8; j++) v[j] = sT[(tc + j) * 72 + dr];
        *(u16x8*)&vt[((size_t)(b * 4 + kh) * 128 + d0 + dr) * 2048 + t0 + tc] = v;
    }
}

// ---------------- causal GQA flash attention ----------------
// Block: 64 Q rows (4 waves x 16), KV tiles of 64. Q in regs, K/V in padded LDS.
__global__ __launch_bounds__(256) void attn(const u16* __restrict__ qkv, const u16* __restrict__ vt,
                                            u16* __restrict__ out) {
    __shared__ alignas(16) u16 sK[64 * 136];
    __shared__ alignas(16) u16 sV[128 * 72];
    __shared__ alignas(16) u16 sP[4 * 16 * 72];
    const int t = threadIdx.x, wave = t >> 6, lane = t & 63;
    const int l15 = lane & 15, hl = lane >> 4;
    const int q0 = blockIdx.x * 64;
    const int h = blockIdx.y & 15, b = blockIdx.y >> 4;
    const int kh = h >> 2;

    const u16* qbase = qkv + (size_t)(b * T_SEQ + q0 + wave * 16 + l15) * 3072 + h * 128;
    bf16x8 qf[4];
#pragma unroll
    for (int c = 0; c < 4; c++) qf[c] = *(const bf16x8*)(qbase + c * 32 + hl * 8);

    float mrow[4], lrow[4];
    f32x4 o[8];
    f32x4 z = {0.f, 0.f, 0.f, 0.f};
#pragma unroll
    for (int r = 0; r < 4; r++) { mrow[r] = -1e30f; lrow[r] = 0.f; }
#pragma unroll
    for (int n8 = 0; n8 < 8; n8++) o[n8] = z;
    const float sc = 0.08838834764831845f;   // 1/sqrt(128)

    for (int kv0 = 0; kv0 <= q0; kv0 += 64) {
        // stage K [64][128] (+8 pad) and Vt [128][64] (+8 pad)
        {
            int rowr = t >> 4, colc = (t & 15) * 8;
#pragma unroll
            for (int i = 0; i < 4; i++) {
                int row = i * 16 + rowr;
                *(u16x8*)&sK[row * 136 + colc] =
                    *(const u16x8*)&qkv[(size_t)(b * T_SEQ + kv0 + row) * 3072 + 2048 + kh * 128 + colc];
            }
            int dr = t >> 3, c2 = (t & 7) * 8;
#pragma unroll
            for (int i = 0; i < 4; i++) {
                int d = i * 32 + dr;
                *(u16x8*)&sV[d * 72 + c2] =
                    *(const u16x8*)&vt[((size_t)(b * 4 + kh) * 128 + d) * 2048 + kv0 + c2];
            }
        }
        __syncthreads();

        // S = Q K^T  (16 rows x 64 cols per wave)
        f32x4 s[4];
#pragma unroll
        for (int n = 0; n < 4; n++) s[n] = z;
#pragma unroll
        for (int n = 0; n < 4; n++)
#pragma unroll
            for (int c = 0; c < 4; c++) {
                bf16x8 kf = *(const bf16x8*)&sK[(n * 16 + l15) * 136 + c * 32 + hl * 8];
                s[n] = __builtin_amdgcn_mfma_f32_16x16x32_bf16(qf[c], kf, s[n], 0, 0, 0);
            }

        // scale + causal mask + online softmax
        float pv[4][4];
#pragma unroll
        for (int n = 0; n < 4; n++)
#pragma unroll
            for (int r = 0; r < 4; r++) {
                float v = s[n][r] * sc;
                int col = kv0 + n * 16 + l15;
                int row = q0 + wave * 16 + hl * 4 + r;
                pv[n][r] = (col <= row) ? v : -1e30f;
            }
#pragma unroll
        for (int r = 0; r < 4; r++) {
            float mx = fmaxf(fmaxf(pv[0][r], pv[1][r]), fmaxf(pv[2][r], pv[3][r]));
#pragma unroll
            for (int off = 1; off < 16; off <<= 1) mx = fmaxf(mx, __shfl_xor(mx, off));
            float mnew = fmaxf(mrow[r], mx);
            float alpha = __expf(mrow[r] - mnew);
            float rsum = 0.f;
#pragma unroll
            for (int n = 0; n < 4; n++) {
                float p = __expf(pv[n][r] - mnew);
                rsum += p;
                sP[(wave * 16 + hl * 4 + r) * 72 + n * 16 + l15] = f2bf(p);
            }
#pragma unroll
            for (int off = 1; off < 16; off <<= 1) rsum += __shfl_xor(rsum, off);
            lrow[r] = lrow[r] * alpha + rsum;
            mrow[r] = mnew;
#pragma unroll
            for (int n8 = 0; n8 < 8; n8++) o[n8][r] *= alpha;
        }

        // O += P V
        bf16x8 pa[2];
#pragma unroll
        for (int k2 = 0; k2 < 2; k2++)
            pa[k2] = *(const bf16x8*)&sP[(wave * 16 + l15) * 72 + k2 * 32 + hl * 8];
#pragma unroll
        for (int n8 = 0; n8 < 8; n8++)
#pragma unroll
            for (int k2 = 0; k2 < 2; k2++) {
                bf16x8 vf = *(const bf16x8*)&sV[(n8 * 16 + l15) * 72 + k2 * 32 + hl * 8];
                o[n8] = __builtin_amdgcn_mfma_f32_16x16x32_bf16(pa[k2], vf, o[n8], 0, 0, 0);
            }
        __syncthreads();
    }

#pragma unroll
    for (int r = 0; r < 4; r++) {
        float inv = 1.f / lrow[r];
        int orow = b * T_SEQ + q0 + wave * 16 + hl * 4 + r;
#pragma unroll
        for (int n8 = 0; n8 < 8; n8++)
            out[(size_t)orow * 2048 + h * 128 + n8 * 16 + l15] = f2bf(o[n8][r] * inv);
    }
}

extern "C" void kernel_launch(void* const* d_in, const int* in_sizes, int n_in,
                              void* d_out, int out_size, void* d_ws, size_t ws_size,
                              hipStream_t stream) {
    const float* x  = (const float*)d_in[0];
    const float* Wq = (const float*)d_in[1];
    const float* Wk = (const float*)d_in[2];
    const float* Wv = (const float*)d_in[3];
    const float* Wp = (const float*)d_in[4];
    const int*   pos = (const int*)d_in[5];

    char* ws = (char*)d_ws;
    u16* xbf   = (u16*)(ws);                        // 4096*2048       bf16
    u16* WtQKV = (u16*)(ws + 16777216);             // 3072*2048       bf16 (rows: Wq^T | Wk^T | Wv^T)
    u16* WtP   = (u16*)(ws + 29360128);             // 2048*2048       bf16
    u16* QKV   = (u16*)(ws + 37748736);             // 4096*3072       bf16
    u16* Vt    = (u16*)(ws + 62914560);             // 2*4*128*2048    bf16
    u16* AO    = (u16*)(ws + 67108864);             // 4096*2048       bf16

    cast_f32_bf16<<<4096, 256, 0, stream>>>(x, xbf, 1048576);
    transpose_cast<<<dim3(32, 32), 256, 0, stream>>>(Wq, WtQKV, 2048);
    transpose_cast<<<dim3(32, 8), 256, 0, stream>>>(Wk, WtQKV + (size_t)2048 * 2048, 512);
    transpose_cast<<<dim3(32, 8), 256, 0, stream>>>(Wv, WtQKV + (size_t)2560 * 2048, 512);
    transpose_cast<<<dim3(32, 32), 256, 0, stream>>>(Wp, WtP, 2048);

    gemm_bt<false><<<dim3(32, 24), 256, 0, stream>>>(xbf, WtQKV, QKV, 4096, 3072, 2048);
    rope_kernel<<<20480, 256, 0, stream>>>(QKV, pos);
    vtrans<<<dim3(32, 2, 8), 256, 0, stream>>>(QKV, Vt);
    attn<<<dim3(32, 32), 256, 0, stream>>>(QKV, Vt, AO);
    gemm_bt<true><<<dim3(32, 16), 256, 0, stream>>>(AO, WtP, d_out, 4096, 2048, 2048);
}